// Round 5
// baseline (247.932 us; speedup 1.0000x reference)
//
#include <hip/hip_runtime.h>
#include <hip/hip_bf16.h>

typedef unsigned short u16;
typedef unsigned int u32;
typedef __attribute__((ext_vector_type(8))) short bf16x8;
typedef __attribute__((ext_vector_type(4))) float f32x4;

#define LOG2E 1.44269504088896340736f
#define QSCALE (0.125f * LOG2E)

// ---------- helpers ----------

__device__ inline u16 f2bf(float f) {            // RNE
  union { float f; u32 u; } v; v.f = f;
  u32 r = v.u + 0x7fffu + ((v.u >> 16) & 1u);
  return (u16)(r >> 16);
}
__device__ inline u16 f2bf_fast(float f) {       // round-half-up (staging)
  u32 u = __builtin_bit_cast(u32, f);
  return (u16)((u + 0x8000u) >> 16);
}

__device__ inline void gload_lds16(const u16* g, u16* l) {
  __builtin_amdgcn_global_load_lds(
      (const __attribute__((address_space(1))) u32*)g,
      (__attribute__((address_space(3))) u32*)l, 16, 0, 0);
}

// DPP move within 16-lane rows (row_ror:N = 0x120+N)
template<int CTRL>
__device__ inline float dppmov(float x) {
  int i = __builtin_bit_cast(int, x);
  int r = __builtin_amdgcn_update_dpp(i, i, CTRL, 0xf, 0xf, false);
  return __builtin_bit_cast(float, r);
}
__device__ inline float rowmax16(float v) {
  v = fmaxf(v, dppmov<0x128>(v));
  v = fmaxf(v, dppmov<0x124>(v));
  v = fmaxf(v, dppmov<0x122>(v));
  v = fmaxf(v, dppmov<0x121>(v));
  return v;
}
__device__ inline float rowsum16(float v) {
  v += dppmov<0x128>(v);
  v += dppmov<0x124>(v);
  v += dppmov<0x122>(v);
  v += dppmov<0x121>(v);
  return v;
}

// ---------- fp32 -> bf16 conversion (weights only) ----------

__global__ void cvt_multi(const float4* __restrict__ s0, const float4* __restrict__ s1,
                          const float4* __restrict__ s2, const float4* __restrict__ s3,
                          ushort4* __restrict__ d0, ushort4* __restrict__ d1,
                          ushort4* __restrict__ d2, ushort4* __restrict__ d3, int n4) {
  const float4* s; ushort4* d;
  switch (blockIdx.y) {
    case 0: s = s0; d = d0; break;
    case 1: s = s1; d = d1; break;
    case 2: s = s2; d = d2; break;
    default: s = s3; d = d3; break;
  }
  int stride = gridDim.x * blockDim.x;
  for (int i = blockIdx.x * blockDim.x + threadIdx.x; i < n4; i += stride) {
    float4 v = s[i];
    ushort4 o;
    o.x = f2bf(v.x); o.y = f2bf(v.y); o.z = f2bf(v.z); o.w = f2bf(v.w);
    d[i] = o;
  }
}

// ---------- per-(b, kv-tile) padding-mask OR flags ----------

__global__ void mask_flags(const unsigned char* __restrict__ mask,
                           unsigned char* __restrict__ flags) {
  int t = threadIdx.x;   // 0..127
  if (t >= 128) return;
  const uint4* p = (const uint4*)(mask + (size_t)t * 64);
  uint4 a = p[0], b = p[1], c = p[2], d = p[3];
  u32 v = a.x | a.y | a.z | a.w | b.x | b.y | b.z | b.w |
          c.x | c.y | c.z | c.w | d.x | d.y | d.z | d.w;
  flags[t] = v ? 1 : 0;
}

struct ARegs { float4 a0, a1, a2, a3; };

// ---------- fused Q/K/V projection, A read directly from fp32 ----------
// A: reg-staged global f32 -> cvt -> ds_write, PIPELINE DEPTH 2 (loads for
// tile kt+2 issued at iteration kt; consumed at kt+1 -> one full iteration of
// latency cover). Loop unrolled x2 so register-set selection is compile-time.
// B (bf16 weights) via global_load_lds double-buffer. XCD-chunked swizzle.

__global__ __launch_bounds__(256) void gemm_qkv_f32a(
    const float* __restrict__ Aqf, const float* __restrict__ Akf, const float* __restrict__ Avf,
    const u16* __restrict__ Wqb, const u16* __restrict__ Wkb, const u16* __restrict__ Wvb,
    const float* __restrict__ bqp, const float* __restrict__ bkp, const float* __restrict__ bvp,
    u16* __restrict__ Qh, u16* __restrict__ Kh, u16* __restrict__ Vt,
    int M, int N, int K) {
  constexpr int BK = 32;
  __shared__ u16 sA[2][128 * BK];
  __shared__ u16 sB[2][128 * BK];

  // ---- XCD-chunked bijective block swizzle (nwg = 1536, %8==0) ----
  const int nx = gridDim.x;                  // 8
  const int nxy = gridDim.x * gridDim.y;     // 512
  const int nwg = nxy * gridDim.z;           // 1536
  const int hw = blockIdx.z * nxy + blockIdx.y * nx + blockIdx.x;
  const int per = nwg >> 3;
  const int lg = (hw & 7) * per + (hw >> 3);
  const int z = lg / nxy;
  const int rem = lg - z * nxy;
  const int m0 = (rem >> 3) * 128;
  const int n0 = (rem & 7) * 128;

  const float* Af = (z == 0) ? Aqf : (z == 1) ? Akf : Avf;
  const u16* Bt   = (z == 0) ? Wqb : (z == 1) ? Wkb : Wvb;
  const float* bias = (z == 0) ? bqp : (z == 1) ? bkp : bvp;

  const int tid = threadIdx.x;
  const int lane = tid & 63;
  const int wave = tid >> 6;
  const int g = lane >> 4;
  const int r = lane & 15;
  const int wr = wave >> 1, wc = wave & 1;

  f32x4 acc[4][4] = {};
  ARegs s0r, s1r;

  const int c0 = tid, c1 = tid + 256;
  const int row0 = c0 >> 2, cc0 = c0 & 3;
  const int row1 = c1 >> 2, cc1 = c1 & 3;

  auto loadA = [&](int kt, ARegs& s) {
    const int k0 = kt * BK;
    const float* p0 = Af + (size_t)(m0 + row0) * K + k0 + cc0 * 8;
    const float* p1 = Af + (size_t)(m0 + row1) * K + k0 + cc1 * 8;
    s.a0 = *(const float4*)(p0);
    s.a1 = *(const float4*)(p0 + 4);
    s.a2 = *(const float4*)(p1);
    s.a3 = *(const float4*)(p1 + 4);
  };
  auto writeA = [&](int buf, ARegs& s) {
    bf16x8 pk0, pk1;
    pk0[0] = (short)f2bf_fast(s.a0.x); pk0[1] = (short)f2bf_fast(s.a0.y);
    pk0[2] = (short)f2bf_fast(s.a0.z); pk0[3] = (short)f2bf_fast(s.a0.w);
    pk0[4] = (short)f2bf_fast(s.a1.x); pk0[5] = (short)f2bf_fast(s.a1.y);
    pk0[6] = (short)f2bf_fast(s.a1.z); pk0[7] = (short)f2bf_fast(s.a1.w);
    pk1[0] = (short)f2bf_fast(s.a2.x); pk1[1] = (short)f2bf_fast(s.a2.y);
    pk1[2] = (short)f2bf_fast(s.a2.z); pk1[3] = (short)f2bf_fast(s.a2.w);
    pk1[4] = (short)f2bf_fast(s.a3.x); pk1[5] = (short)f2bf_fast(s.a3.y);
    pk1[6] = (short)f2bf_fast(s.a3.z); pk1[7] = (short)f2bf_fast(s.a3.w);
    *(bf16x8*)(&sA[buf][c0 * 8]) = pk0;
    *(bf16x8*)(&sA[buf][c1 * 8]) = pk1;
  };
  auto stageB = [&](int buf, int kt) {
    const int k0 = kt * BK;
#pragma unroll
    for (int i = 0; i < 2; ++i) {
      int c = tid + i * 256;
      int rw = c >> 2, cc = c & 3;
      gload_lds16(Bt + (size_t)(n0 + rw) * K + k0 + cc * 8, &sB[buf][0] + c * 8);
    }
  };
  auto compute = [&](const u16* a_base, const u16* b_base) {
    bf16x8 avf[4], bvf[4];
#pragma unroll
    for (int i = 0; i < 4; ++i) {
      avf[i] = *(const bf16x8*)(a_base + (wr * 64 + i * 16 + r) * BK + g * 8);
      bvf[i] = *(const bf16x8*)(b_base + (wc * 64 + i * 16 + r) * BK + g * 8);
    }
#pragma unroll
    for (int i = 0; i < 4; ++i)
#pragma unroll
      for (int j = 0; j < 4; ++j)
        acc[i][j] = __builtin_amdgcn_mfma_f32_16x16x32_bf16(avf[i], bvf[j], acc[i][j], 0, 0, 0);
  };

  const int NT = K / BK;   // 32 (even)

  // prologue: tile0 A -> buf0; tile1 A loads in flight; B tile0 staged
  loadA(0, s0r);
  writeA(0, s0r);          // vmcnt wait on tile0 loads only
  loadA(1, s1r);
  stageB(0, 0);

  for (int kt = 0; kt < NT; kt += 2) {
    // ---- even iteration: cur buf0, consumes s1r (tile kt+1), loads s0r ----
    __syncthreads();
    if (kt + 1 < NT) {
      stageB(1, kt + 1);
      writeA(1, s1r);                       // data loaded one iteration ago
      if (kt + 2 < NT) loadA(kt + 2, s0r);  // issue 2 tiles ahead
    }
    compute(&sA[0][0], &sB[0][0]);

    // ---- odd iteration: cur buf1, consumes s0r (tile kt+2), loads s1r ----
    if (kt + 1 < NT) {
      __syncthreads();
      if (kt + 2 < NT) {
        stageB(0, kt + 2);
        writeA(0, s0r);
        if (kt + 3 < NT) loadA(kt + 3, s1r);
      }
      compute(&sA[1][0], &sB[1][0]);
    }
  }

#pragma unroll
  for (int i = 0; i < 4; ++i) {
    int rowb = m0 + wr * 64 + i * 16 + g * 4;
#pragma unroll
    for (int j = 0; j < 4; ++j) {
      int col = n0 + wc * 64 + j * 16 + r;
      float bv = bias[col];
#pragma unroll
      for (int q = 0; q < 4; ++q) {
        int row = rowb + q;
        float v = acc[i][j][q] + bv;
        int b = row >> 10, t = row & 1023, h = col >> 6, d = col & 63;
        if (z == 0) {
          Qh[((((size_t)b * 16 + h) << 10) + t) * 64 + d] = f2bf(v * QSCALE);
        } else if (z == 1) {
          Kh[((((size_t)b * 16 + h) << 10) + t) * 64 + d] = f2bf(v);
        } else {
          Vt[(((size_t)b * 16 + h) * 64 + d) * 1024 + t] = f2bf(v);
        }
      }
    }
  }
}

// ---------- O-projection GEMM: bf16 A x bf16 W^T -> fp32 out, XCD swizzle ----------

__global__ __launch_bounds__(256) void gemm_o(
    const u16* __restrict__ A, const u16* __restrict__ Bt,
    const float* __restrict__ bias, float* __restrict__ Cout,
    int M, int N, int K) {
  constexpr int BK = 32;
  __shared__ u16 sA[2][128 * BK];
  __shared__ u16 sB[2][128 * BK];

  const int nx = gridDim.x;                  // 8
  const int nwg = gridDim.x * gridDim.y;     // 512
  const int hw = blockIdx.y * nx + blockIdx.x;
  const int per = nwg >> 3;
  const int lg = (hw & 7) * per + (hw >> 3);
  const int m0 = (lg >> 3) * 128;
  const int n0 = (lg & 7) * 128;

  const int tid = threadIdx.x;
  const int lane = tid & 63;
  const int wave = tid >> 6;
  const int g = lane >> 4;
  const int r = lane & 15;
  const int wr = wave >> 1, wc = wave & 1;

  f32x4 acc[4][4] = {};

  auto stage = [&](int buf, int kt) {
    const int k0 = kt * BK;
#pragma unroll
    for (int i = 0; i < 2; ++i) {
      int c = tid + i * 256;
      int row = c >> 2, cc = c & 3;
      gload_lds16(A + (size_t)(m0 + row) * K + k0 + cc * 8, &sA[buf][0] + c * 8);
    }
#pragma unroll
    for (int i = 0; i < 2; ++i) {
      int c = tid + i * 256;
      int row = c >> 2, cc = c & 3;
      gload_lds16(Bt + (size_t)(n0 + row) * K + k0 + cc * 8, &sB[buf][0] + c * 8);
    }
  };

  stage(0, 0);
  const int NT = K / BK;
  for (int kt = 0; kt < NT; ++kt) {
    __syncthreads();
    if (kt + 1 < NT) stage((kt + 1) & 1, kt + 1);
    const u16* a_base = &sA[kt & 1][0];
    const u16* b_base = &sB[kt & 1][0];
    bf16x8 avf[4], bvf[4];
#pragma unroll
    for (int i = 0; i < 4; ++i) {
      avf[i] = *(const bf16x8*)(a_base + (wr * 64 + i * 16 + r) * BK + g * 8);
      bvf[i] = *(const bf16x8*)(b_base + (wc * 64 + i * 16 + r) * BK + g * 8);
    }
#pragma unroll
    for (int i = 0; i < 4; ++i)
#pragma unroll
      for (int j = 0; j < 4; ++j)
        acc[i][j] = __builtin_amdgcn_mfma_f32_16x16x32_bf16(avf[i], bvf[j], acc[i][j], 0, 0, 0);
  }

#pragma unroll
  for (int i = 0; i < 4; ++i) {
    int rowb = m0 + wr * 64 + i * 16 + g * 4;
#pragma unroll
    for (int j = 0; j < 4; ++j) {
      int col = n0 + wc * 64 + j * 16 + r;
      float bv = bias[col];
#pragma unroll
      for (int q = 0; q < 4; ++q) {
        int row = rowb + q;
        Cout[(size_t)row * N + col] = acc[i][j][q] + bv;
      }
    }
  }
}

// ---------- flash attention (causal + padding flags) ----------

__global__ __launch_bounds__(256) void attn_fwd(
    const u16* __restrict__ Qh, const u16* __restrict__ Kh,
    const u16* __restrict__ Vt, const unsigned char* __restrict__ mask,
    const unsigned char* __restrict__ padflags,
    u16* __restrict__ O) {
  constexpr int S = 1024, DH = 64;
  __shared__ u16 sK[2][64 * 64];
  __shared__ u16 sV[2][64 * 64];
  __shared__ u16 sP[4][16 * 64];

  const int tid = threadIdx.x, lane = tid & 63, wave = tid >> 6;
  const int g = lane >> 4, r = lane & 15;
  const int bh = blockIdx.x;
  const int qt = (int)gridDim.y - 1 - (int)blockIdx.y;
  const int b = bh >> 4, h = bh & 15;
  const int qw = qt * 128 + wave * 32;

  bf16x8 qf[2][2];
#pragma unroll
  for (int u = 0; u < 2; ++u) {
    const u16* Qb = Qh + ((size_t)bh * S + qw + u * 16 + r) * DH;
    qf[u][0] = *(const bf16x8*)(Qb + g * 8);
    qf[u][1] = *(const bf16x8*)(Qb + 32 + g * 8);
  }

  f32x4 acc[2][4] = {};
  float mrun[2][4], lrun[2][4];
#pragma unroll
  for (int u = 0; u < 2; ++u)
#pragma unroll
    for (int i = 0; i < 4; ++i) { mrun[u][i] = -INFINITY; lrun[u][i] = 0.f; }

  auto stage = [&](int buf, int kvt) {
    const int s0k = kvt * 64;
#pragma unroll
    for (int i = 0; i < 2; ++i) {
      int c = tid + i * 256;
      int row = c >> 3;
      int cc = (c & 7) ^ (row & 7);
      gload_lds16(Kh + ((size_t)bh * S + s0k + row) * DH + cc * 8, &sK[buf][0] + c * 8);
      gload_lds16(Vt + ((size_t)bh * DH + row) * S + s0k + cc * 8, &sV[buf][0] + c * 8);
    }
  };

  const int NT = 2 * (qt + 1);
  stage(0, 0);
  for (int kvt = 0; kvt < NT; ++kvt) {
    __syncthreads();
    if (kvt + 1 < NT) stage((kvt + 1) & 1, kvt + 1);
    const int cur = kvt & 1;
    const int s0 = kvt * 64;
    const bool pad = padflags[b * 16 + (s0 >> 6)] != 0;
    const u16* Kb = &sK[cur][0];
    const u16* Vb = &sV[cur][0];
    u16* Pw = &sP[wave][0];

#pragma unroll
    for (int u = 0; u < 2; ++u) {
      const int qg = qw + u * 16;
      if (s0 > qg + 15) continue;
      const bool diag = (s0 + 63 > qg);

      f32x4 sc[4] = {};
#pragma unroll
      for (int ss = 0; ss < 4; ++ss) {
#pragma unroll
        for (int kc = 0; kc < 2; ++kc) {
          int krow = ss * 16 + r;
          int byteoff = krow * 128 + kc * 64 + g * 16;
          bf16x8 kf = *(const bf16x8*)((const char*)Kb + (byteoff ^ ((krow & 7) << 4)));
          sc[ss] = __builtin_amdgcn_mfma_f32_16x16x32_bf16(qf[u][kc], kf, sc[ss], 0, 0, 0);
        }
      }

      float sv[4][4];
      float pmax[4] = {-INFINITY, -INFINITY, -INFINITY, -INFINITY};
#pragma unroll
      for (int ss = 0; ss < 4; ++ss) {
        float padd = 0.f;
        if (pad) {
          int s_g = s0 + ss * 16 + r;
          if (mask[(size_t)b * S + s_g]) padd = -INFINITY;
        }
#pragma unroll
        for (int reg = 0; reg < 4; ++reg) {
          float v = sc[ss][reg] + padd;
          if (diag) {
            int s_g = s0 + ss * 16 + r;
            int q_g = qg + g * 4 + reg;
            if (s_g > q_g) v = -INFINITY;
          }
          sv[ss][reg] = v;
          pmax[reg] = fmaxf(pmax[reg], v);
        }
      }
#pragma unroll
      for (int reg = 0; reg < 4; ++reg) {
        float m = rowmax16(pmax[reg]);
        float newm = fmaxf(mrun[u][reg], m);
        float alpha = (newm == -INFINITY) ? 1.f : exp2f(mrun[u][reg] - newm);
        mrun[u][reg] = newm;
        float rs = 0.f;
#pragma unroll
        for (int ss = 0; ss < 4; ++ss) {
          float p = (newm == -INFINITY) ? 0.f : exp2f(sv[ss][reg] - newm);
          sv[ss][reg] = p;
          rs += p;
        }
        rs = rowsum16(rs);
        lrun[u][reg] = lrun[u][reg] * alpha + rs;
#pragma unroll
        for (int df = 0; df < 4; ++df) acc[u][df][reg] *= alpha;
      }

#pragma unroll
      for (int ss = 0; ss < 4; ++ss) {
#pragma unroll
        for (int reg = 0; reg < 4; ++reg) {
          int qrow = g * 4 + reg;
          int byteoff = qrow * 128 + (ss * 16 + r) * 2;
          u32 bits = __builtin_bit_cast(u32, sv[ss][reg]);
          *(u16*)((char*)Pw + (byteoff ^ ((qrow & 7) << 4))) = (u16)(bits >> 16);
        }
      }

#pragma unroll
      for (int sc2 = 0; sc2 < 2; ++sc2) {
        int pbyte = r * 128 + sc2 * 64 + g * 16;
        bf16x8 pf = *(const bf16x8*)((const char*)Pw + (pbyte ^ ((r & 7) << 4)));
#pragma unroll
        for (int df = 0; df < 4; ++df) {
          int vrow = df * 16 + r;
          int vbyte = vrow * 128 + sc2 * 64 + g * 16;
          bf16x8 vf = *(const bf16x8*)((const char*)Vb + (vbyte ^ ((vrow & 7) << 4)));
          acc[u][df] = __builtin_amdgcn_mfma_f32_16x16x32_bf16(pf, vf, acc[u][df], 0, 0, 0);
        }
      }
    }
  }

#pragma unroll
  for (int u = 0; u < 2; ++u) {
#pragma unroll
    for (int reg = 0; reg < 4; ++reg) {
      float l = lrun[u][reg];
      float inv = (l > 0.f) ? 1.f / l : 0.f;
      int t = qw + u * 16 + g * 4 + reg;
#pragma unroll
      for (int df = 0; df < 4; ++df) {
        float vo = acc[u][df][reg] * inv;
        O[((size_t)b * 1024 + t) * 1024 + h * 64 + df * 16 + r] = f2bf(vo);
      }
    }
  }
}

// ---------- launch ----------

extern "C" void kernel_launch(void* const* d_in, const int* in_sizes, int n_in,
                              void* d_out, int out_size, void* d_ws, size_t ws_size,
                              hipStream_t stream) {
  const float* q  = (const float*)d_in[0];
  const float* k  = (const float*)d_in[1];
  const float* v  = (const float*)d_in[2];
  const unsigned char* mask = (const unsigned char*)d_in[3];
  const float* Wq = (const float*)d_in[4];
  const float* bq = (const float*)d_in[5];
  const float* Wk = (const float*)d_in[6];
  const float* bk = (const float*)d_in[7];
  const float* Wv = (const float*)d_in[8];
  const float* bv = (const float*)d_in[9];
  const float* Wo = (const float*)d_in[10];
  const float* bo = (const float*)d_in[11];

  const int M = 8192, N = 1024, K = 1024;
  const size_t MB = 1u << 20;
  char* ws = (char*)d_ws;

  u16* AttO = (u16*)(ws);                 // 16MB (attn output, bf16)
  u16* Qh   = (u16*)(ws + 16 * MB);
  u16* Kh   = (u16*)(ws + 32 * MB);
  u16* Vt   = (u16*)(ws + 48 * MB);
  u16* Wqb  = (u16*)(ws + 64 * MB);
  u16* Wkb  = Wqb + (1u << 20);
  u16* Wvb  = Wkb + (1u << 20);
  u16* Wob  = Wvb + (1u << 20);
  unsigned char* flags = (unsigned char*)(ws + 72 * MB);

  cvt_multi<<<dim3(256, 4), 256, 0, stream>>>(
      (const float4*)Wq, (const float4*)Wk, (const float4*)Wv, (const float4*)Wo,
      (ushort4*)Wqb, (ushort4*)Wkb, (ushort4*)Wvb, (ushort4*)Wob, (N * K) / 4);
  mask_flags<<<1, 128, 0, stream>>>(mask, flags);

  gemm_qkv_f32a<<<dim3(N / 128, M / 128, 3), 256, 0, stream>>>(
      q, k, v, Wqb, Wkb, Wvb, bq, bk, bv, Qh, Kh, Vt, M, N, K);

  attn_fwd<<<dim3(128, 8), 256, 0, stream>>>(Qh, Kh, Vt, mask, flags, AttO);

  gemm_o<<<dim3(N / 128, M / 128), 256, 0, stream>>>(
      AttO, Wob, bo, (float*)d_out, M, N, K);
}

// Round 6
// 216.460 us; speedup vs baseline: 1.1454x; 1.1454x over previous
//
#include <hip/hip_runtime.h>
#include <hip/hip_bf16.h>

typedef unsigned short u16;
typedef unsigned int u32;
typedef __attribute__((ext_vector_type(8))) short bf16x8;
typedef __attribute__((ext_vector_type(4))) float f32x4;
typedef __attribute__((ext_vector_type(4))) unsigned int u32x4v;

#define LOG2E 1.44269504088896340736f
#define QSCALE (0.125f * LOG2E)

// ---------- helpers ----------

__device__ inline u16 f2bf(float f) {            // RNE
  union { float f; u32 u; } v; v.f = f;
  u32 r = v.u + 0x7fffu + ((v.u >> 16) & 1u);
  return (u16)(r >> 16);
}

__device__ inline void gload_lds16(const void* g, void* l) {
  __builtin_amdgcn_global_load_lds(
      (const __attribute__((address_space(1))) u32*)g,
      (__attribute__((address_space(3))) u32*)l, 16, 0, 0);
}

// DPP move within 16-lane rows (row_ror:N = 0x120+N)
template<int CTRL>
__device__ inline float dppmov(float x) {
  int i = __builtin_bit_cast(int, x);
  int r = __builtin_amdgcn_update_dpp(i, i, CTRL, 0xf, 0xf, false);
  return __builtin_bit_cast(float, r);
}
__device__ inline float rowmax16(float v) {
  v = fmaxf(v, dppmov<0x128>(v));
  v = fmaxf(v, dppmov<0x124>(v));
  v = fmaxf(v, dppmov<0x122>(v));
  v = fmaxf(v, dppmov<0x121>(v));
  return v;
}
__device__ inline float rowsum16(float v) {
  v += dppmov<0x128>(v);
  v += dppmov<0x124>(v);
  v += dppmov<0x122>(v);
  v += dppmov<0x121>(v);
  return v;
}

// ---------- fp32 -> bf16 conversion (weights only) ----------

__global__ void cvt_multi(const float4* __restrict__ s0, const float4* __restrict__ s1,
                          const float4* __restrict__ s2, const float4* __restrict__ s3,
                          ushort4* __restrict__ d0, ushort4* __restrict__ d1,
                          ushort4* __restrict__ d2, ushort4* __restrict__ d3, int n4) {
  const float4* s; ushort4* d;
  switch (blockIdx.y) {
    case 0: s = s0; d = d0; break;
    case 1: s = s1; d = d1; break;
    case 2: s = s2; d = d2; break;
    default: s = s3; d = d3; break;
  }
  int stride = gridDim.x * blockDim.x;
  for (int i = blockIdx.x * blockDim.x + threadIdx.x; i < n4; i += stride) {
    float4 v = s[i];
    ushort4 o;
    o.x = f2bf(v.x); o.y = f2bf(v.y); o.z = f2bf(v.z); o.w = f2bf(v.w);
    d[i] = o;
  }
}

// ---------- per-(b, kv-tile) padding-mask OR flags ----------

__global__ void mask_flags(const unsigned char* __restrict__ mask,
                           unsigned char* __restrict__ flags) {
  int t = threadIdx.x;   // 0..127
  if (t >= 128) return;
  const uint4* p = (const uint4*)(mask + (size_t)t * 64);
  uint4 a = p[0], b = p[1], c = p[2], d = p[3];
  u32 v = a.x | a.y | a.z | a.w | b.x | b.y | b.z | b.w |
          c.x | c.y | c.z | c.w | d.x | d.y | d.z | d.w;
  flags[t] = v ? 1 : 0;
}

// ---------- fused Q/K/V projection, A staged as RAW f32 via global_load_lds ----------
// A tile [128][32] f32 (16KB/buf), XOR-swizzled (slot ^= row&7, 16B units);
// f32->bf16 truncation happens at fragment-read via v_perm_b32 (high halves).
// B tile [128][32] bf16, XOR-swizzled (slot ^= (row>>1)&3) -> 2-way (free).
// All staging is fire-and-forget DMA drained at the barrier (round-3 pattern).
// XCD-chunked bijective block swizzle for L2 locality.

__global__ __launch_bounds__(256) void gemm_qkv_f32a(
    const float* __restrict__ Aqf, const float* __restrict__ Akf, const float* __restrict__ Avf,
    const u16* __restrict__ Wqb, const u16* __restrict__ Wkb, const u16* __restrict__ Wvb,
    const float* __restrict__ bqp, const float* __restrict__ bkp, const float* __restrict__ bvp,
    u16* __restrict__ Qh, u16* __restrict__ Kh, u16* __restrict__ Vt,
    int M, int N, int K) {
  constexpr int BK = 32;
  __shared__ float sAf[2][128 * BK];   // 2 x 16 KB
  __shared__ u16   sB [2][128 * BK];   // 2 x 8 KB

  // ---- XCD-chunked bijective block swizzle (nwg = 8*64*3 = 1536, %8==0) ----
  const int nx = gridDim.x;                  // 8
  const int nxy = gridDim.x * gridDim.y;     // 512
  const int nwg = nxy * gridDim.z;           // 1536
  const int hw = blockIdx.z * nxy + blockIdx.y * nx + blockIdx.x;
  const int per = nwg >> 3;
  const int lg = (hw & 7) * per + (hw >> 3);
  const int z = lg / nxy;
  const int rem = lg - z * nxy;
  const int m0 = (rem >> 3) * 128;
  const int n0 = (rem & 7) * 128;

  const float* Af = (z == 0) ? Aqf : (z == 1) ? Akf : Avf;
  const u16* Bt   = (z == 0) ? Wqb : (z == 1) ? Wkb : Wvb;
  const float* bias = (z == 0) ? bqp : (z == 1) ? bkp : bvp;

  const int tid = threadIdx.x;
  const int lane = tid & 63;
  const int wave = tid >> 6;
  const int g = lane >> 4;
  const int r = lane & 15;
  const int wr = wave >> 1, wc = wave & 1;

  f32x4 acc[4][4] = {};

  auto stage = [&](int buf, int kt) {
    const int k0 = kt * BK;
    // A: 1024 chunks of 16B (4 floats), pre-swizzled source
#pragma unroll
    for (int i = 0; i < 4; ++i) {
      int c = tid + i * 256;
      int row = c >> 3, cc = c & 7;
      int scc = cc ^ (row & 7);
      gload_lds16(Af + (size_t)(m0 + row) * K + k0 + scc * 4,
                  (char*)&sAf[buf][0] + c * 16);
    }
    // B: 512 chunks of 16B (8 bf16), pre-swizzled source
#pragma unroll
    for (int i = 0; i < 2; ++i) {
      int c = tid + i * 256;
      int row = c >> 2, cc = c & 3;
      int scc = cc ^ ((row >> 1) & 3);
      gload_lds16(Bt + (size_t)(n0 + row) * K + k0 + scc * 8,
                  (char*)&sB[buf][0] + c * 16);
    }
  };

  auto compute = [&](int buf) {
    const char* aB = (const char*)&sAf[buf][0];
    const char* bB = (const char*)&sB[buf][0];
    bf16x8 avf[4], bvf[4];
#pragma unroll
    for (int i = 0; i < 4; ++i) {
      int arow = wr * 64 + i * 16 + r;
      const char* rb = aB + arow * 128;
      int s7 = arow & 7;
      uint4 q0 = *(const uint4*)(rb + (((g * 2)     ^ s7) * 16));
      uint4 q1 = *(const uint4*)(rb + (((g * 2 + 1) ^ s7) * 16));
      u32x4v w;
      w.x = __builtin_amdgcn_perm(q0.y, q0.x, 0x07060302u);  // bf16(f0)|bf16(f1)<<16
      w.y = __builtin_amdgcn_perm(q0.w, q0.z, 0x07060302u);
      w.z = __builtin_amdgcn_perm(q1.y, q1.x, 0x07060302u);
      w.w = __builtin_amdgcn_perm(q1.w, q1.z, 0x07060302u);
      avf[i] = __builtin_bit_cast(bf16x8, w);
      int brow = wc * 64 + i * 16 + r;
      bvf[i] = *(const bf16x8*)(bB + brow * 64 + ((g ^ ((brow >> 1) & 3)) * 16));
    }
#pragma unroll
    for (int i = 0; i < 4; ++i)
#pragma unroll
      for (int j = 0; j < 4; ++j)
        acc[i][j] = __builtin_amdgcn_mfma_f32_16x16x32_bf16(avf[i], bvf[j], acc[i][j], 0, 0, 0);
  };

  stage(0, 0);
  const int NT = K / BK;
  for (int kt = 0; kt < NT; ++kt) {
    __syncthreads();                  // drains DMA -> buf[kt&1] ready
    if (kt + 1 < NT) stage((kt + 1) & 1, kt + 1);
    compute(kt & 1);
  }

#pragma unroll
  for (int i = 0; i < 4; ++i) {
    int rowb = m0 + wr * 64 + i * 16 + g * 4;
#pragma unroll
    for (int j = 0; j < 4; ++j) {
      int col = n0 + wc * 64 + j * 16 + r;
      float bv = bias[col];
#pragma unroll
      for (int q = 0; q < 4; ++q) {
        int row = rowb + q;
        float v = acc[i][j][q] + bv;
        int b = row >> 10, t = row & 1023, h = col >> 6, d = col & 63;
        if (z == 0) {
          Qh[((((size_t)b * 16 + h) << 10) + t) * 64 + d] = f2bf(v * QSCALE);
        } else if (z == 1) {
          Kh[((((size_t)b * 16 + h) << 10) + t) * 64 + d] = f2bf(v);
        } else {
          Vt[(((size_t)b * 16 + h) * 64 + d) * 1024 + t] = f2bf(v);
        }
      }
    }
  }
}

// ---------- O-projection GEMM: bf16 A x bf16 W^T -> fp32 out ----------
// Both tiles [128][32] bf16, XOR-swizzled (slot ^= (row>>1)&3). XCD swizzle.

__global__ __launch_bounds__(256) void gemm_o(
    const u16* __restrict__ A, const u16* __restrict__ Bt,
    const float* __restrict__ bias, float* __restrict__ Cout,
    int M, int N, int K) {
  constexpr int BK = 32;
  __shared__ u16 sA[2][128 * BK];
  __shared__ u16 sB[2][128 * BK];

  const int nx = gridDim.x;                  // 8
  const int nwg = gridDim.x * gridDim.y;     // 512
  const int hw = blockIdx.y * nx + blockIdx.x;
  const int per = nwg >> 3;
  const int lg = (hw & 7) * per + (hw >> 3);
  const int m0 = (lg >> 3) * 128;
  const int n0 = (lg & 7) * 128;

  const int tid = threadIdx.x;
  const int lane = tid & 63;
  const int wave = tid >> 6;
  const int g = lane >> 4;
  const int r = lane & 15;
  const int wr = wave >> 1, wc = wave & 1;

  f32x4 acc[4][4] = {};

  auto stage = [&](int buf, int kt) {
    const int k0 = kt * BK;
#pragma unroll
    for (int i = 0; i < 2; ++i) {
      int c = tid + i * 256;
      int row = c >> 2, cc = c & 3;
      int scc = cc ^ ((row >> 1) & 3);
      gload_lds16(A + (size_t)(m0 + row) * K + k0 + scc * 8,
                  (char*)&sA[buf][0] + c * 16);
    }
#pragma unroll
    for (int i = 0; i < 2; ++i) {
      int c = tid + i * 256;
      int row = c >> 2, cc = c & 3;
      int scc = cc ^ ((row >> 1) & 3);
      gload_lds16(Bt + (size_t)(n0 + row) * K + k0 + scc * 8,
                  (char*)&sB[buf][0] + c * 16);
    }
  };

  stage(0, 0);
  const int NT = K / BK;
  for (int kt = 0; kt < NT; ++kt) {
    __syncthreads();
    if (kt + 1 < NT) stage((kt + 1) & 1, kt + 1);
    const char* aB = (const char*)&sA[kt & 1][0];
    const char* bB = (const char*)&sB[kt & 1][0];
    bf16x8 avf[4], bvf[4];
#pragma unroll
    for (int i = 0; i < 4; ++i) {
      int arow = wr * 64 + i * 16 + r;
      avf[i] = *(const bf16x8*)(aB + arow * 64 + ((g ^ ((arow >> 1) & 3)) * 16));
      int brow = wc * 64 + i * 16 + r;
      bvf[i] = *(const bf16x8*)(bB + brow * 64 + ((g ^ ((brow >> 1) & 3)) * 16));
    }
#pragma unroll
    for (int i = 0; i < 4; ++i)
#pragma unroll
      for (int j = 0; j < 4; ++j)
        acc[i][j] = __builtin_amdgcn_mfma_f32_16x16x32_bf16(avf[i], bvf[j], acc[i][j], 0, 0, 0);
  }

#pragma unroll
  for (int i = 0; i < 4; ++i) {
    int rowb = m0 + wr * 64 + i * 16 + g * 4;
#pragma unroll
    for (int j = 0; j < 4; ++j) {
      int col = n0 + wc * 64 + j * 16 + r;
      float bv = bias[col];
#pragma unroll
      for (int q = 0; q < 4; ++q) {
        int row = rowb + q;
        Cout[(size_t)row * N + col] = acc[i][j][q] + bv;
      }
    }
  }
}

// ---------- flash attention (causal + padding flags) ----------

__global__ __launch_bounds__(256) void attn_fwd(
    const u16* __restrict__ Qh, const u16* __restrict__ Kh,
    const u16* __restrict__ Vt, const unsigned char* __restrict__ mask,
    const unsigned char* __restrict__ padflags,
    u16* __restrict__ O) {
  constexpr int S = 1024, DH = 64;
  __shared__ u16 sK[2][64 * 64];
  __shared__ u16 sV[2][64 * 64];
  __shared__ u16 sP[4][16 * 64];

  const int tid = threadIdx.x, lane = tid & 63, wave = tid >> 6;
  const int g = lane >> 4, r = lane & 15;
  const int bh = blockIdx.x;
  const int qt = (int)gridDim.y - 1 - (int)blockIdx.y;
  const int b = bh >> 4, h = bh & 15;
  const int qw = qt * 128 + wave * 32;

  bf16x8 qf[2][2];
#pragma unroll
  for (int u = 0; u < 2; ++u) {
    const u16* Qb = Qh + ((size_t)bh * S + qw + u * 16 + r) * DH;
    qf[u][0] = *(const bf16x8*)(Qb + g * 8);
    qf[u][1] = *(const bf16x8*)(Qb + 32 + g * 8);
  }

  f32x4 acc[2][4] = {};
  float mrun[2][4], lrun[2][4];
#pragma unroll
  for (int u = 0; u < 2; ++u)
#pragma unroll
    for (int i = 0; i < 4; ++i) { mrun[u][i] = -INFINITY; lrun[u][i] = 0.f; }

  auto stage = [&](int buf, int kvt) {
    const int s0k = kvt * 64;
#pragma unroll
    for (int i = 0; i < 2; ++i) {
      int c = tid + i * 256;
      int row = c >> 3;
      int cc = (c & 7) ^ (row & 7);
      gload_lds16(Kh + ((size_t)bh * S + s0k + row) * DH + cc * 8, &sK[buf][0] + c * 8);
      gload_lds16(Vt + ((size_t)bh * DH + row) * S + s0k + cc * 8, &sV[buf][0] + c * 8);
    }
  };

  const int NT = 2 * (qt + 1);
  stage(0, 0);
  for (int kvt = 0; kvt < NT; ++kvt) {
    __syncthreads();
    if (kvt + 1 < NT) stage((kvt + 1) & 1, kvt + 1);
    const int cur = kvt & 1;
    const int s0 = kvt * 64;
    const bool pad = padflags[b * 16 + (s0 >> 6)] != 0;
    const u16* Kb = &sK[cur][0];
    const u16* Vb = &sV[cur][0];
    u16* Pw = &sP[wave][0];

#pragma unroll
    for (int u = 0; u < 2; ++u) {
      const int qg = qw + u * 16;
      if (s0 > qg + 15) continue;
      const bool diag = (s0 + 63 > qg);

      f32x4 sc[4] = {};
#pragma unroll
      for (int ss = 0; ss < 4; ++ss) {
#pragma unroll
        for (int kc = 0; kc < 2; ++kc) {
          int krow = ss * 16 + r;
          int byteoff = krow * 128 + kc * 64 + g * 16;
          bf16x8 kf = *(const bf16x8*)((const char*)Kb + (byteoff ^ ((krow & 7) << 4)));
          sc[ss] = __builtin_amdgcn_mfma_f32_16x16x32_bf16(qf[u][kc], kf, sc[ss], 0, 0, 0);
        }
      }

      float sv[4][4];
      float pmax[4] = {-INFINITY, -INFINITY, -INFINITY, -INFINITY};
#pragma unroll
      for (int ss = 0; ss < 4; ++ss) {
        float padd = 0.f;
        if (pad) {
          int s_g = s0 + ss * 16 + r;
          if (mask[(size_t)b * S + s_g]) padd = -INFINITY;
        }
#pragma unroll
        for (int reg = 0; reg < 4; ++reg) {
          float v = sc[ss][reg] + padd;
          if (diag) {
            int s_g = s0 + ss * 16 + r;
            int q_g = qg + g * 4 + reg;
            if (s_g > q_g) v = -INFINITY;
          }
          sv[ss][reg] = v;
          pmax[reg] = fmaxf(pmax[reg], v);
        }
      }
#pragma unroll
      for (int reg = 0; reg < 4; ++reg) {
        float m = rowmax16(pmax[reg]);
        float newm = fmaxf(mrun[u][reg], m);
        float alpha = (newm == -INFINITY) ? 1.f : exp2f(mrun[u][reg] - newm);
        mrun[u][reg] = newm;
        float rs = 0.f;
#pragma unroll
        for (int ss = 0; ss < 4; ++ss) {
          float p = (newm == -INFINITY) ? 0.f : exp2f(sv[ss][reg] - newm);
          sv[ss][reg] = p;
          rs += p;
        }
        rs = rowsum16(rs);
        lrun[u][reg] = lrun[u][reg] * alpha + rs;
#pragma unroll
        for (int df = 0; df < 4; ++df) acc[u][df][reg] *= alpha;
      }

#pragma unroll
      for (int ss = 0; ss < 4; ++ss) {
#pragma unroll
        for (int reg = 0; reg < 4; ++reg) {
          int qrow = g * 4 + reg;
          int byteoff = qrow * 128 + (ss * 16 + r) * 2;
          u32 bits = __builtin_bit_cast(u32, sv[ss][reg]);
          *(u16*)((char*)Pw + (byteoff ^ ((qrow & 7) << 4))) = (u16)(bits >> 16);
        }
      }

#pragma unroll
      for (int sc2 = 0; sc2 < 2; ++sc2) {
        int pbyte = r * 128 + sc2 * 64 + g * 16;
        bf16x8 pf = *(const bf16x8*)((const char*)Pw + (pbyte ^ ((r & 7) << 4)));
#pragma unroll
        for (int df = 0; df < 4; ++df) {
          int vrow = df * 16 + r;
          int vbyte = vrow * 128 + sc2 * 64 + g * 16;
          bf16x8 vf = *(const bf16x8*)((const char*)Vb + (vbyte ^ ((vrow & 7) << 4)));
          acc[u][df] = __builtin_amdgcn_mfma_f32_16x16x32_bf16(pf, vf, acc[u][df], 0, 0, 0);
        }
      }
    }
  }

#pragma unroll
  for (int u = 0; u < 2; ++u) {
#pragma unroll
    for (int reg = 0; reg < 4; ++reg) {
      float l = lrun[u][reg];
      float inv = (l > 0.f) ? 1.f / l : 0.f;
      int t = qw + u * 16 + g * 4 + reg;
#pragma unroll
      for (int df = 0; df < 4; ++df) {
        float vo = acc[u][df][reg] * inv;
        O[((size_t)b * 1024 + t) * 1024 + h * 64 + df * 16 + r] = f2bf(vo);
      }
    }
  }
}

// ---------- launch ----------

extern "C" void kernel_launch(void* const* d_in, const int* in_sizes, int n_in,
                              void* d_out, int out_size, void* d_ws, size_t ws_size,
                              hipStream_t stream) {
  const float* q  = (const float*)d_in[0];
  const float* k  = (const float*)d_in[1];
  const float* v  = (const float*)d_in[2];
  const unsigned char* mask = (const unsigned char*)d_in[3];
  const float* Wq = (const float*)d_in[4];
  const float* bq = (const float*)d_in[5];
  const float* Wk = (const float*)d_in[6];
  const float* bk = (const float*)d_in[7];
  const float* Wv = (const float*)d_in[8];
  const float* bv = (const float*)d_in[9];
  const float* Wo = (const float*)d_in[10];
  const float* bo = (const float*)d_in[11];

  const int M = 8192, N = 1024, K = 1024;
  const size_t MB = 1u << 20;
  char* ws = (char*)d_ws;

  u16* AttO = (u16*)(ws);                 // 16MB (attn output, bf16)
  u16* Qh   = (u16*)(ws + 16 * MB);
  u16* Kh   = (u16*)(ws + 32 * MB);
  u16* Vt   = (u16*)(ws + 48 * MB);
  u16* Wqb  = (u16*)(ws + 64 * MB);
  u16* Wkb  = Wqb + (1u << 20);
  u16* Wvb  = Wkb + (1u << 20);
  u16* Wob  = Wvb + (1u << 20);
  unsigned char* flags = (unsigned char*)(ws + 72 * MB);

  cvt_multi<<<dim3(256, 4), 256, 0, stream>>>(
      (const float4*)Wq, (const float4*)Wk, (const float4*)Wv, (const float4*)Wo,
      (ushort4*)Wqb, (ushort4*)Wkb, (ushort4*)Wvb, (ushort4*)Wob, (N * K) / 4);
  mask_flags<<<1, 128, 0, stream>>>(mask, flags);

  gemm_qkv_f32a<<<dim3(N / 128, M / 128, 3), 256, 0, stream>>>(
      q, k, v, Wqb, Wkb, Wvb, bq, bk, bv, Qh, Kh, Vt, M, N, K);

  attn_fwd<<<dim3(128, 8), 256, 0, stream>>>(Qh, Kh, Vt, mask, flags, AttO);

  gemm_o<<<dim3(N / 128, M / 128), 256, 0, stream>>>(
      AttO, Wob, bo, (float*)d_out, M, N, K);
}